// Round 4
// baseline (117.133 us; speedup 1.0000x reference)
//
#include <hip/hip_runtime.h>

#define NN 2048
#define DD 128
#define KK 16

typedef float f4 __attribute__((ext_vector_type(4)));   // native vec for nontemporal

// One wave (64 threads) per output row (b,i). Lane owns indices j = t*256+lane*4+c,
// t in [0,8), c in [0,4). No LDS: rescans re-read own elements from global (L2-hot),
// gate row is rebuilt from a per-lane 32-bit selection mask.
__global__ __launch_bounds__(64, 8) void rc_topk_kernel(
    const float* __restrict__ s,        // [B,N,D]
    const float* __restrict__ noise,    // [B,N,N]
    const int*   __restrict__ adj,      // [B,N,N]
    const int*   __restrict__ active,   // [B,N]
    const int*   __restrict__ act,      // [B,N]
    float* __restrict__ ctx,            // [B,N,D]
    float* __restrict__ gate,           // [B,N,N]
    float* __restrict__ w)              // [B,N,N]
{
    const int lane = threadIdx.x;          // 0..63
    const int row  = blockIdx.x;           // b*N + i
    const int b    = row >> 11;            // /2048
    const long long rowoff = (long long)row * NN;

    if (act[row] == 0) {
        const f4 z4 = (f4)0.0f;
        #pragma unroll
        for (int t = 0; t < 8; ++t) {
            const int j = t * 256 + lane * 4;
            __builtin_nontemporal_store(z4, (f4*)&gate[rowoff + j]);
            __builtin_nontemporal_store(z4, (f4*)&w[rowoff + j]);
        }
        *(float2*)&ctx[(long long)row * DD + lane * 2] = make_float2(0.f, 0.f);
        return;
    }

    // ---- Pass 1: per-lane top-2 (ascending j, strict '>' => min index on ties) ----
    float k1v = -4.0f, k2v = -4.0f; int k1j = 0, k2j = 0;
    #pragma unroll
    for (int t = 0; t < 8; ++t) {
        const int j = t * 256 + lane * 4;
        const float4 nz = *(const float4*)&noise[rowoff + j];
        const int4   ad = *(const int4*)&adj[rowoff + j];
        const int4   am = *(const int4*)&active[b * NN + j];
        const float v0 = (ad.x > 0 && am.x > 0) ? nz.x : -1.0f;
        const float v1 = (ad.y > 0 && am.y > 0) ? nz.y : -1.0f;
        const float v2 = (ad.z > 0 && am.z > 0) ? nz.z : -1.0f;
        const float v3 = (ad.w > 0 && am.w > 0) ? nz.w : -1.0f;
        if (v0 > k1v) { k2v = k1v; k2j = k1j; k1v = v0; k1j = j;     }
        else if (v0 > k2v) { k2v = v0; k2j = j;     }
        if (v1 > k1v) { k2v = k1v; k2j = k1j; k1v = v1; k1j = j + 1; }
        else if (v1 > k2v) { k2v = v1; k2j = j + 1; }
        if (v2 > k1v) { k2v = k1v; k2j = k1j; k1v = v2; k1j = j + 2; }
        else if (v2 > k2v) { k2v = v2; k2j = j + 2; }
        if (v3 > k1v) { k2v = k1v; k2j = k1j; k1v = v3; k1j = j + 3; }
        else if (v3 > k2v) { k2v = v3; k2j = j + 3; }
    }
    bool k2dirty = false;
    unsigned int selmask = 0;              // bit (t*4+c): own element selected

    // ---- 16x extraction ----
    int cnt = 0;
    float2 acc  = make_float2(0.f, 0.f);
    float2 pend = make_float2(0.f, 0.f);
    for (int k = 0; k < KK; ++k) {
        float mv = k1v;
        #pragma unroll
        for (int off = 32; off; off >>= 1) mv = fmaxf(mv, __shfl_xor(mv, off, 64));
        if (mv < 0.0f) break;              // no valid candidates left
        const unsigned long long tied = __ballot(k1v == mv);
        int rj;
        if (__popcll(tied) == 1) {         // common case: unique value
            rj = __shfl(k1j, (int)__builtin_ctzll(tied), 64);
        } else {                           // exact tie: min index wins
            int pj = (k1v == mv) ? k1j : 0x7FFFFFFF;
            #pragma unroll
            for (int off = 32; off; off >>= 1) {
                const int o = __shfl_xor(pj, off, 64);
                pj = o < pj ? o : pj;
            }
            rj = pj;
        }
        acc.x += pend.x; acc.y += pend.y;  // consume previous iteration's s-load
        pend = *(const float2*)&s[((long long)(b * NN + rj)) * DD + lane * 2];
        ++cnt;
        if (k1v == mv && k1j == rj) {      // unique owner lane
            selmask |= 1u << (((rj >> 8) << 2) | (rj & 3));
            if (!k2dirty) { k1v = k2v; k1j = k2j; k2dirty = true; }
            else {                         // 2nd win: rescan own 32 from L2
                float c1v = -4.0f, c2v = -4.0f; int c1j = 0, c2j = 0;
                #pragma unroll
                for (int t = 0; t < 8; ++t) {
                    const int j = t * 256 + lane * 4;
                    const float4 nz = *(const float4*)&noise[rowoff + j];
                    const int4   ad = *(const int4*)&adj[rowoff + j];
                    const int4   am = *(const int4*)&active[b * NN + j];
                    const unsigned mb = selmask >> (t * 4);
                    const float v0 = (ad.x > 0 && am.x > 0 && !(mb & 1u)) ? nz.x : -1.0f;
                    const float v1 = (ad.y > 0 && am.y > 0 && !(mb & 2u)) ? nz.y : -1.0f;
                    const float v2 = (ad.z > 0 && am.z > 0 && !(mb & 4u)) ? nz.z : -1.0f;
                    const float v3 = (ad.w > 0 && am.w > 0 && !(mb & 8u)) ? nz.w : -1.0f;
                    if (v0 > c1v) { c2v = c1v; c2j = c1j; c1v = v0; c1j = j;     }
                    else if (v0 > c2v) { c2v = v0; c2j = j;     }
                    if (v1 > c1v) { c2v = c1v; c2j = c1j; c1v = v1; c1j = j + 1; }
                    else if (v1 > c2v) { c2v = v1; c2j = j + 1; }
                    if (v2 > c1v) { c2v = c1v; c2j = c1j; c1v = v2; c1j = j + 2; }
                    else if (v2 > c2v) { c2v = v2; c2j = j + 2; }
                    if (v3 > c1v) { c2v = c1v; c2j = c1j; c1v = v3; c1j = j + 3; }
                    else if (v3 > c2v) { c2v = v3; c2j = j + 3; }
                }
                k1v = c1v; k1j = c1j; k2v = c2v; k2j = c2j; k2dirty = false;
            }
        }
    }
    acc.x += pend.x; acc.y += pend.y;      // last pending row

    const float inv = 1.0f / (float)(cnt > 1 ? cnt : 1);

    // ---- Output stream: gate/w rebuilt from selmask (lane owns every address) ----
    #pragma unroll
    for (int t = 0; t < 8; ++t) {
        const int j = t * 256 + lane * 4;
        const unsigned mb = selmask >> (t * 4);
        f4 g;
        g.x = (mb & 1u) ? 1.0f : 0.0f;
        g.y = (mb & 2u) ? 1.0f : 0.0f;
        g.z = (mb & 4u) ? 1.0f : 0.0f;
        g.w = (mb & 8u) ? 1.0f : 0.0f;
        __builtin_nontemporal_store(g, (f4*)&gate[rowoff + j]);
        const f4 wv = g * inv;
        __builtin_nontemporal_store(wv, (f4*)&w[rowoff + j]);
    }

    // ---- ctx ----
    *(float2*)&ctx[(long long)row * DD + lane * 2] = make_float2(acc.x * inv, acc.y * inv);
}

extern "C" void kernel_launch(void* const* d_in, const int* in_sizes, int n_in,
                              void* d_out, int out_size, void* d_ws, size_t ws_size,
                              hipStream_t stream) {
    const float* s      = (const float*)d_in[0];
    const float* noise  = (const float*)d_in[1];
    const int*   adj    = (const int*)d_in[2];
    const int*   active = (const int*)d_in[3];
    const int*   act    = (const int*)d_in[4];

    const int B = in_sizes[3] / NN;                  // active_mask is [B,N]
    const long long ctxN  = (long long)B * NN * DD;
    const long long gateN = (long long)B * NN * NN;

    float* ctxp = (float*)d_out;
    float* gatep = ctxp + ctxN;
    float* wp = gatep + gateN;

    rc_topk_kernel<<<B * NN, 64, 0, stream>>>(s, noise, adj, active, act, ctxp, gatep, wp);
}